// Round 4
// baseline (424.915 us; speedup 1.0000x reference)
//
#include <hip/hip_runtime.h>
#include <math.h>

// Round 4: same verified split-FP16 numerics as round 3; 512-thread blocks
// (8 waves x 64x32 output) -> 4 waves/SIMD occupancy for latency hiding.

#define N_ROWS 262144
#define FEAT   128
#define HID    256
#define TM     64
#define NT     512
#define NBLK   (N_ROWS/TM)

typedef _Float16 h8v __attribute__((ext_vector_type(8)));   // 8 x fp16 (4 VGPRs)
typedef float    f4v __attribute__((ext_vector_type(4)));   // MFMA accumulator

// d_ws: W1/W2 fp16 hi/lo in MFMA-fragment order (393216 B total)
#define WS_W1H 0
#define WS_W1L 65536
#define WS_W2H 131072
#define WS_W2L 262144

// LDS (bytes). Timeline overlays:
//   phase1: A hi/lo [0,32768) ; phase2: H1 hi/lo [0,65536) ; phase3: H2 f32 [0,65536)
#define OFF_AH  0
#define OFF_AL  16384
#define OFF_H1H 0
#define OFF_H1L 32768
#define W3SEC   1168                      // [8 sections][32 rows][9] f32, +16B skew
#define OFF_W3  65536
#define OFF_B3  (OFF_W3 + 8*W3SEC)        // 74880
#define OFF_RS  (OFF_B3 + 64)             // 74944  [64][12] f32
#define OFF_MS  (OFF_RS + TM*12*4)        // 78016  [64][12] f32
#define SMEM_SZ (OFF_MS + TM*12*4)        // 81088 B -> 2 blocks/CU

__device__ __forceinline__ unsigned short hbits(_Float16 h) {
    return __builtin_bit_cast(unsigned short, h);
}

// ---- prep: pack W1,W2 to fp16 hi/lo in fragment order (8 elems/thread) ----
// fragment elem e = (((ks*16+cb)*64)+fl)*8 + j  <->  W[k][n],
// k = ks*32 + (fl>>4)*8 + j, n = cb*16 + (fl&15).
__global__ __launch_bounds__(256)
void prep_weights(const float* __restrict__ W1, const float* __restrict__ W2,
                  unsigned char* __restrict__ ws) {
    int g = blockIdx.x * 256 + threadIdx.x;          // 12288 threads total
    int base = g * 8;
    const float* W; unsigned short* dh; unsigned short* dl; int e;
    if (base < FEAT * HID) {
        W = W1; dh = (unsigned short*)(ws + WS_W1H); dl = (unsigned short*)(ws + WS_W1L); e = base;
    } else if (base < FEAT * HID + HID * HID) {
        W = W2; dh = (unsigned short*)(ws + WS_W2H); dl = (unsigned short*)(ws + WS_W2L); e = base - FEAT * HID;
    } else return;
    int fl = (e >> 3) & 63, cb = (e >> 9) & 15, ks = e >> 13;
    int k0 = ks * 32 + ((fl >> 4) << 3), n = cb * 16 + (fl & 15);
    unsigned short hs[8], ls[8];
#pragma unroll
    for (int j = 0; j < 8; ++j) {
        float v = W[(size_t)(k0 + j) * HID + n];
        _Float16 h = (_Float16)v, l = (_Float16)(v - (float)h);
        hs[j] = hbits(h); ls[j] = hbits(l);
    }
    *(uint4*)(dh + e) = *(const uint4*)hs;
    *(uint4*)(dl + e) = *(const uint4*)ls;
}

// ---- split-fp16 MFMA layer: acc += A @ B over K = KSTEPS*32 (3 passes) ----
// wave qc owns output cols [qc*32, qc*32+32): col-blocks cb = qc*2 + ct.
template<int KSTEPS, int ROWSTRIDE>
__device__ __forceinline__ void mfma_layer(const unsigned char* AH, const unsigned char* AL,
                                           const h8v* __restrict__ BH, const h8v* __restrict__ BL,
                                           f4v acc[4][2], int lane, int qc) {
#pragma unroll
    for (int ks = 0; ks < KSTEPS; ++ks) {
        h8v bh[2], bl[2];
#pragma unroll
        for (int ct = 0; ct < 2; ++ct) {
            int fi = ((ks * 16 + qc * 2 + ct) << 6) + lane;
            bh[ct] = BH[fi]; bl[ct] = BL[fi];
        }
        h8v ah[4], al[4];
#pragma unroll
        for (int rt = 0; rt < 4; ++rt) {
            int row = rt * 16 + (lane & 15);
            unsigned byt = (unsigned)(row * ROWSTRIDE + ks * 64 + ((lane >> 4) << 4));
            byt ^= (unsigned)((row & 7) << 4);          // bank swizzle
            ah[rt] = *(const h8v*)(AH + byt);
            al[rt] = *(const h8v*)(AL + byt);
        }
#pragma unroll
        for (int ct = 0; ct < 2; ++ct)
#pragma unroll
            for (int rt = 0; rt < 4; ++rt) {
                acc[rt][ct] = __builtin_amdgcn_mfma_f32_16x16x32_f16(ah[rt], bh[ct], acc[rt][ct], 0, 0, 0);
                acc[rt][ct] = __builtin_amdgcn_mfma_f32_16x16x32_f16(ah[rt], bl[ct], acc[rt][ct], 0, 0, 0);
                acc[rt][ct] = __builtin_amdgcn_mfma_f32_16x16x32_f16(al[rt], bh[ct], acc[rt][ct], 0, 0, 0);
            }
    }
}

__global__ __launch_bounds__(NT, 4)
void fused_main(const float* __restrict__ rot, const float* __restrict__ feat,
                const float* __restrict__ b1, const float* __restrict__ b2,
                const float* __restrict__ W3, const float* __restrict__ b3,
                const unsigned char* __restrict__ ws, float* __restrict__ out) {
    __shared__ __align__(16) unsigned char smem[SMEM_SZ];
    const int tid = threadIdx.x, lane = tid & 63, w = tid >> 6;   // w: 0..7
    const int row0 = blockIdx.x * TM;

    // ---- stage: feature -> A hi/lo (swizzled), W3 (sectioned), b3, rotation ----
    {
        const float4* f4 = (const float4*)(feat + (size_t)row0 * FEAT);
#pragma unroll
        for (int it = 0; it < TM * FEAT / 4 / NT; ++it) {
            int t = it * NT + tid;
            float4 v = f4[t];
            int row = t >> 5, c4 = t & 31;
            unsigned byt = (unsigned)(row * 256 + c4 * 8) ^ (unsigned)((row & 7) << 4);
            _Float16 h0 = (_Float16)v.x, h1v = (_Float16)v.y, h2v = (_Float16)v.z, h3v = (_Float16)v.w;
            _Float16 l0 = (_Float16)(v.x - (float)h0), l1v = (_Float16)(v.y - (float)h1v);
            _Float16 l2v = (_Float16)(v.z - (float)h2v), l3v = (_Float16)(v.w - (float)h3v);
            uint2 hp, lp;
            hp.x = (unsigned)hbits(h0)  | ((unsigned)hbits(h1v) << 16);
            hp.y = (unsigned)hbits(h2v) | ((unsigned)hbits(h3v) << 16);
            lp.x = (unsigned)hbits(l0)  | ((unsigned)hbits(l1v) << 16);
            lp.y = (unsigned)hbits(l2v) | ((unsigned)hbits(l3v) << 16);
            *(uint2*)(smem + OFF_AH + byt) = hp;
            *(uint2*)(smem + OFF_AL + byt) = lp;
        }
        for (int t = tid; t < HID * 9; t += NT) {      // W3 sectioned per 32-col group
            int c = t / 9, o = t - 9 * c;
            *(float*)(smem + OFF_W3 + (c >> 5) * W3SEC + (c & 31) * 36 + o * 4) = W3[t];
        }
        if (tid < 9) ((float*)(smem + OFF_B3))[tid] = b3[tid];
        float* Rs = (float*)(smem + OFF_RS);
        for (int t = tid; t < TM * 9; t += NT)
            Rs[(t / 9) * 12 + (t % 9)] = rot[(size_t)row0 * 9 + t];
    }
    __syncthreads();

    // ---- layer 1: H1 = relu(A @ W1 + b1), split-fp16 ----
    f4v acc[4][2];
#pragma unroll
    for (int i = 0; i < 4; ++i)
#pragma unroll
        for (int j = 0; j < 2; ++j) acc[i][j] = (f4v)0.0f;
    mfma_layer<4, 256>(smem + OFF_AH, smem + OFF_AL,
                       (const h8v*)(ws + WS_W1H), (const h8v*)(ws + WS_W1L), acc, lane, w);
    __syncthreads();          // A fully consumed before H1 overlays it
#pragma unroll
    for (int ct = 0; ct < 2; ++ct) {
        int col = (w * 2 + ct) * 16 + (lane & 15);
        float bias = b1[col];
#pragma unroll
        for (int rt = 0; rt < 4; ++rt)
#pragma unroll
            for (int r = 0; r < 4; ++r) {
                int row = rt * 16 + ((lane >> 4) << 2) + r;   // C/D: col=lane&15, row=(lane>>4)*4+reg
                float v = fmaxf(acc[rt][ct][r] + bias, 0.0f);
                _Float16 h = (_Float16)v, l = (_Float16)(v - (float)h);
                unsigned byt = (unsigned)(row * 512 + col * 2) ^ (unsigned)((row & 7) << 4);
                *(unsigned short*)(smem + OFF_H1H + byt) = hbits(h);
                *(unsigned short*)(smem + OFF_H1L + byt) = hbits(l);
            }
    }
    __syncthreads();

    // ---- layer 2: H2 = relu(H1 @ W2 + b2), split-fp16 ----
#pragma unroll
    for (int i = 0; i < 4; ++i)
#pragma unroll
        for (int j = 0; j < 2; ++j) acc[i][j] = (f4v)0.0f;
    mfma_layer<8, 512>(smem + OFF_H1H, smem + OFF_H1L,
                       (const h8v*)(ws + WS_W2H), (const h8v*)(ws + WS_W2L), acc, lane, w);
    __syncthreads();          // H1 fully consumed before H2 overlays it
#pragma unroll
    for (int ct = 0; ct < 2; ++ct) {
        int col = (w * 2 + ct) * 16 + (lane & 15);
        float bias = b2[col];
#pragma unroll
        for (int rt = 0; rt < 4; ++rt)
#pragma unroll
            for (int r = 0; r < 4; ++r) {
                int row = rt * 16 + ((lane >> 4) << 2) + r;
                unsigned byt = (unsigned)(row * 1024 + col * 4) ^ (unsigned)((row & 7) << 4);
                *(float*)(smem + byt) = fmaxf(acc[rt][ct][r] + bias, 0.0f);   // H2 f32, swizzled
            }
    }
    __syncthreads();

    // ---- layer 3 (fp32): lane (r, kg) -> 9 partials over 32-col group kg ----
    const int r3 = (w << 3) + (lane & 7), kg = lane >> 3;     // 64 rows x 8 groups
    float p[9];
#pragma unroll
    for (int o = 0; o < 9; ++o) p[o] = 0.0f;
#pragma unroll 4
    for (int j = 0; j < 8; ++j) {
        int col = kg * 32 + j * 4;
        unsigned byt = (unsigned)(r3 * 1024 + col * 4) ^ (unsigned)((r3 & 7) << 4);
        float4 h = *(const float4*)(smem + byt);
        const float* wrow = (const float*)(smem + OFF_W3 + kg * W3SEC + (j * 4) * 36);
#pragma unroll
        for (int e = 0; e < 4; ++e) {
            float hv = (e == 0) ? h.x : (e == 1) ? h.y : (e == 2) ? h.z : h.w;
            const float* wr = wrow + e * 9;
#pragma unroll
            for (int o = 0; o < 9; ++o) p[o] += hv * wr[o];
        }
    }
#pragma unroll
    for (int o = 0; o < 9; ++o) {
        p[o] += __shfl_xor(p[o], 8);
        p[o] += __shfl_xor(p[o], 16);
        p[o] += __shfl_xor(p[o], 32);
    }

    // ---- tail (lanes kg==0: 8 rows per wave): X = (M+I)@R, Newton polar ----
    {
        float* Rs = (float*)(smem + OFF_RS);
        float* Ms = (float*)(smem + OFF_MS);
        const float* b3s = (const float*)(smem + OFF_B3);
        if (kg == 0) {
            const int r = r3;
            const float m0 = p[0] + b3s[0] + 1.0f, m1 = p[1] + b3s[1],        m2 = p[2] + b3s[2];
            const float m3 = p[3] + b3s[3],        m4 = p[4] + b3s[4] + 1.0f, m5 = p[5] + b3s[5];
            const float m6 = p[6] + b3s[6],        m7 = p[7] + b3s[7],        m8 = p[8] + b3s[8] + 1.0f;
            const float r0 = Rs[r*12+0], r1 = Rs[r*12+1], r2 = Rs[r*12+2];
            const float r3v = Rs[r*12+3], r4 = Rs[r*12+4], r5 = Rs[r*12+5];
            const float r6 = Rs[r*12+6], r7 = Rs[r*12+7], r8 = Rs[r*12+8];

            float x0 = m0*r0 + m1*r3v + m2*r6;
            float x1 = m0*r1 + m1*r4  + m2*r7;
            float x2 = m0*r2 + m1*r5  + m2*r8;
            float x3 = m3*r0 + m4*r3v + m5*r6;
            float x4 = m3*r1 + m4*r4  + m5*r7;
            float x5 = m3*r2 + m4*r5  + m5*r8;
            float x6 = m6*r0 + m7*r3v + m8*r6;
            float x7 = m6*r1 + m7*r4  + m8*r7;
            float x8 = m6*r2 + m7*r5  + m8*r8;

#pragma unroll 1
            for (int it = 0; it < 16; ++it) {
                const float c0 = x4*x8 - x5*x7;
                const float c1 = x5*x6 - x3*x8;
                const float c2 = x3*x7 - x4*x6;
                const float c3 = x2*x7 - x1*x8;
                const float c4 = x0*x8 - x2*x6;
                const float c5 = x1*x6 - x0*x7;
                const float c6 = x1*x5 - x2*x4;
                const float c7 = x2*x3 - x0*x5;
                const float c8 = x0*x4 - x1*x3;
                const float det = x0*c0 + x1*c1 + x2*c2;
                const float ad  = fmaxf(fabsf(det), 1e-30f);
                const float mu  = 1.0f / cbrtf(ad);
                const float dsafe = copysignf(ad, det);
                const float s1 = 0.5f * mu;
                const float s2 = 0.5f / (mu * dsafe);
                x0 = s1*x0 + s2*c0;  x1 = s1*x1 + s2*c1;  x2 = s1*x2 + s2*c2;
                x3 = s1*x3 + s2*c3;  x4 = s1*x4 + s2*c4;  x5 = s1*x5 + s2*c5;
                x6 = s1*x6 + s2*c6;  x7 = s1*x7 + s2*c7;  x8 = s1*x8 + s2*c8;
            }
            Ms[r*12+0] = x0; Ms[r*12+1] = x1; Ms[r*12+2] = x2;
            Ms[r*12+3] = x3; Ms[r*12+4] = x4; Ms[r*12+5] = x5;
            Ms[r*12+6] = x6; Ms[r*12+7] = x7; Ms[r*12+8] = x8;
        }
    }
    __syncthreads();

    // ---- output: out (N*9) then logdet zeros (N) ----
    {
        float* Ms = (float*)(smem + OFF_MS);
        for (int t = tid; t < TM * 9; t += NT)
            out[(size_t)row0 * 9 + t] = Ms[(t / 9) * 12 + (t % 9)];
        for (int t = tid; t < TM; t += NT)
            out[(size_t)N_ROWS * 9 + row0 + t] = 0.0f;
    }
}

extern "C" void kernel_launch(void* const* d_in, const int* in_sizes, int n_in,
                              void* d_out, int out_size, void* d_ws, size_t ws_size,
                              hipStream_t stream) {
    const float* rot  = (const float*)d_in[0];
    const float* feat = (const float*)d_in[1];
    const float* W1   = (const float*)d_in[2];
    const float* b1   = (const float*)d_in[3];
    const float* W2   = (const float*)d_in[4];
    const float* b2   = (const float*)d_in[5];
    const float* W3   = (const float*)d_in[6];
    const float* b3   = (const float*)d_in[7];
    float* out = (float*)d_out;
    unsigned char* ws = (unsigned char*)d_ws;
    (void)in_sizes; (void)n_in; (void)out_size; (void)ws_size;

    hipLaunchKernelGGL(prep_weights, dim3(48), dim3(256), 0, stream, W1, W2, ws);
    hipLaunchKernelGGL(fused_main, dim3(NBLK), dim3(NT), 0, stream,
                       rot, feat, b1, b2, W3, b3, ws, out);
}